// Round 12
// baseline (194.127 us; speedup 1.0000x reference)
//
#include <hip/hip_runtime.h>
#include <hip/hip_bf16.h>
#include <stdint.h>

// Problem dims (fixed): S=1024, B=4, E=1024, H=16, D=64, M=S*B=4096
// scaling = D^-0.5 = 0.125; log2e folded into q-scale and bias table so the
// attention softmax uses raw exp2.

typedef short bf16x8 __attribute__((ext_vector_type(8)));
typedef _Float16 f16x8 __attribute__((ext_vector_type(8)));
typedef float f32x4 __attribute__((ext_vector_type(4)));
typedef float f32x16 __attribute__((ext_vector_type(16)));
typedef unsigned uint32x2 __attribute__((ext_vector_type(2)));

#define MFMA_BF16(a, b, c) __builtin_amdgcn_mfma_f32_16x16x32_bf16((a), (b), (c), 0, 0, 0)
#define MFMA_F16(a, b, c) __builtin_amdgcn_mfma_f32_16x16x32_f16((a), (b), (c), 0, 0, 0)
#define MFMA32_BF16(a, b, c) __builtin_amdgcn_mfma_f32_32x32x16_bf16((a), (b), (c), 0, 0, 0)

#define LOG2E 1.44269504088896f
#define LN2 0.693147180559945f

__device__ __forceinline__ unsigned short f2bf(float x) {
  union { float f; unsigned u; } v; v.f = x;
  unsigned r = v.u + 0x7fffu + ((v.u >> 16) & 1u);  // RNE
  return (unsigned short)(r >> 16);
}
__device__ __forceinline__ float bf2f(unsigned short u) {
  union { unsigned u; float f; } v; v.u = ((unsigned)u) << 16;
  return v.f;
}
__device__ __forceinline__ unsigned short f2h(float x) {  // RNE via v_cvt_f16_f32
  union { _Float16 h; unsigned short u; } v; v.h = (_Float16)x;
  return v.u;
}
// pack 2 fp32 -> 2 bf16 (RNE) in one u32 (v_cvt_pk_bf16_f32 on gfx950)
__device__ __forceinline__ unsigned pk_bf2(float a, float b) {
  union { __hip_bfloat162 h2; unsigned u; } v;
  v.h2 = __float22bfloat162_rn(float2{a, b});
  return v.u;
}

// async global->LDS 16B: lane's data lands at (wave-uniform base) + lane*16.
__device__ __forceinline__ void gload_lds16(const void* g, void* l) {
  __builtin_amdgcn_global_load_lds(
      (const __attribute__((address_space(1))) unsigned int*)g,
      (__attribute__((address_space(3))) unsigned int*)l, 16, 0, 0);
}

// LDS chunk swizzle for 64B rows (4 chunks of 16B)
__device__ __forceinline__ int swz(int row) { return (row ^ (row >> 2)) & 3; }

// ---------------- fused prep: query cvt/transpose + weight prep + relbias ----------------
__global__ __launch_bounds__(256) void prep_kernel(
    const float* __restrict__ query, const float* __restrict__ q_w,
    const float* __restrict__ k_w, const float* __restrict__ v_w,
    const float* __restrict__ out_w, const float* __restrict__ rel_emb,
    unsigned short* __restrict__ q_bf, unsigned short* __restrict__ wq,
    unsigned short* __restrict__ wk, unsigned short* __restrict__ wv,
    unsigned short* __restrict__ ow_h,   // f16 out_w
    float* __restrict__ bias_f) {        // f32, 16 x 2056 (last 9 zero-padded)
  int i = blockIdx.x * 256 + threadIdx.x;
  if (i < 1048576) {
    // query: (S,B,E) fp32 -> (B,S,E) bf16, 4 elems per thread
    int e4 = (i & 255) << 2;
    int sb = i >> 8;
    int s = sb >> 2, b = sb & 3;
    float4 q4 = *(const float4*)(query + ((size_t)i << 2));
    ushort4 o;
    o.x = f2bf(q4.x); o.y = f2bf(q4.y); o.z = f2bf(q4.z); o.w = f2bf(q4.w);
    *(ushort4*)&q_bf[((size_t)(b * 1024 + s) << 10) | e4] = o;
  } else if (i < 1310720) {
    int j = (i - 1048576) << 2;
    float4 a = *(const float4*)(q_w + j);
    float4 b = *(const float4*)(k_w + j);
    float4 c = *(const float4*)(v_w + j);
    float4 d = *(const float4*)(out_w + j);
    ushort4 o;
    o.x = f2bf(a.x); o.y = f2bf(a.y); o.z = f2bf(a.z); o.w = f2bf(a.w);
    *(ushort4*)&wq[j] = o;
    o.x = f2bf(b.x); o.y = f2bf(b.y); o.z = f2bf(b.z); o.w = f2bf(b.w);
    *(ushort4*)&wk[j] = o;
    o.x = f2bf(c.x); o.y = f2bf(c.y); o.z = f2bf(c.z); o.w = f2bf(c.w);
    *(ushort4*)&wv[j] = o;
    o.x = f2h(d.x); o.y = f2h(d.y); o.z = f2h(d.z); o.w = f2h(d.w);
    *(ushort4*)&ow_h[j] = o;
  } else {
    int idx = i - 1310720;
    if (idx >= 2056) return;
    if (idx >= 2047) {
#pragma unroll
      for (int h = 0; h < 16; ++h) bias_f[h * 2056 + idx] = 0.f;
      return;
    }
    int rel = idx - 1023;
    int n = rel < 0 ? -rel : rel;
    int ret = rel > 0 ? 16 : 0;
    int bucket;
    if (n < 8) {
      bucket = ret + n;
    } else {
      int large = 8 + (int)(logf((float)n / 8.0f) / logf(16.0f) * 8.0f);
      if (large > 15) large = 15;
      bucket = ret + large;
    }
#pragma unroll
    for (int h = 0; h < 16; ++h)
      bias_f[h * 2056 + idx] = rel_emb[bucket * 16 + h] * LOG2E;
  }
}

// ---------------- fused QKV projection GEMM + gate (BK=64, dbuf DMA) ----------------
// R21: BK=32 -> BK=64 (m97-exact config: 128B K-rows, 16 kt iterations, 32
// MFMA/wave per barrier instead of 16) — halves the per-MFMA barrier/drain
// overhead that held qkv at 608 TF (m97/m103 measure 874-912 TF for this
// tile at BK=64 on this chip). LDS 64KB (2x32KB) -> 2 blocks/CU; m132's
// BK=128 regression noted, pre-committed revert if qkv >= 38us. 8-chunk XOR
// swizzle (chunk ^ (row&7)), same as attn's K tiles. Gate fusion unchanged.
__global__ __launch_bounds__(256, 2) void qkv_gemm_kernel(
    const unsigned short* __restrict__ A, const unsigned short* __restrict__ Wq,
    const unsigned short* __restrict__ Wk, const unsigned short* __restrict__ Wv,
    const float* __restrict__ qb, const float* __restrict__ kb, const float* __restrict__ vb,
    const float* __restrict__ grep_w, const float* __restrict__ grep_b,
    const float* __restrict__ grep_a,
    unsigned short* __restrict__ qh,   // (B,H,S,D) scaled q
    unsigned short* __restrict__ kh,   // (B,H,S,D)
    unsigned short* __restrict__ vT,   // (B,H,D,S)
    float* __restrict__ gate)          // (B*H, S)
{
  __shared__ __align__(16) char smem[65536];
  const int tid = threadIdx.x, lane = tid & 63;
  const int wv_ = tid >> 6;
  const int nt = blockIdx.x;
  const int mt = blockIdx.y;
  const int mat = nt >> 3;
  const unsigned short* W = mat == 0 ? Wq : (mat == 1 ? Wk : Wv);
  const int n0 = (nt & 7) * 128;
  const int m0 = mt * 128;
  const int moff = (wv_ & 1) * 64;
  const int noff = (wv_ >> 1) * 64;
  const int q15 = lane & 15, quad = lane >> 4;

  // operand-role select (uniform per block): q/k read af from the W region.
  const int abase = (mat < 2) ? 16384 : 0;
  const int bbase2 = 16384 - abase;
  const int aoff = (mat < 2) ? noff : moff;
  const int boff = (mat < 2) ? moff : noff;

  f32x4 acc[4][4] = {};
  const char* Ab = (const char*)A;
  const char* Wb = (const char*)W;

  // staging geometry: 128 rows x 128B per matrix tile (16KB); 4 DMA insts
  // of 4KB each per matrix; 8-chunk XOR swizzle within each row.
  int st_row[4], st_g[4];
#pragma unroll
  for (int c = 0; c < 4; ++c) {
    int o = c * 4096 + tid * 16;
    int row = o >> 7, p = (o >> 4) & 7;
    st_row[c] = row;
    st_g[c] = p ^ (row & 7);
  }

#define QKV_STAGE(kt, buf)                                                     \
  {                                                                            \
    char* bb = smem + (buf)*32768;                                             \
    _Pragma("unroll") for (int c = 0; c < 4; ++c) {                            \
      int o = c * 4096 + tid * 16;                                             \
      size_t ga = (size_t)(m0 + st_row[c]) * 2048 + (size_t)(kt)*128 + st_g[c] * 16; \
      size_t gb = (size_t)(n0 + st_row[c]) * 2048 + (size_t)(kt)*128 + st_g[c] * 16; \
      gload_lds16(Ab + ga, bb + o);                                            \
      gload_lds16(Wb + gb, bb + 16384 + o);                                    \
    }                                                                          \
  }

  QKV_STAGE(0, 0);
  for (int kt = 0; kt < 16; ++kt) {
    __syncthreads();
    const char* base = smem + (kt & 1) * 32768;
    if (kt < 15) QKV_STAGE(kt + 1, (kt + 1) & 1);

#pragma unroll
    for (int kk = 0; kk < 2; ++kk) {
      bf16x8 af[4], bfr[4];
#pragma unroll
      for (int i = 0; i < 4; ++i) {
        int ra = aoff + i * 16 + q15;
        int rb = boff + i * 16 + q15;
        af[i] = *(const bf16x8*)(base + abase + ra * 128 +
                                 (((kk * 4 + quad) ^ (ra & 7)) << 4));
        bfr[i] = *(const bf16x8*)(base + bbase2 + rb * 128 +
                                  (((kk * 4 + quad) ^ (rb & 7)) << 4));
      }
#pragma unroll
      for (int i = 0; i < 4; ++i)
#pragma unroll
        for (int j = 0; j < 4; ++j) acc[i][j] = MFMA_BF16(af[i], bfr[j], acc[i][j]);
    }
  }
#undef QKV_STAGE

  const int bidx = m0 >> 10;
  if (mat < 2) {
    // acc[i][j]: i -> n-blocks (d-dim rows), j -> s-blocks (cols)
    const float* barr = mat == 0 ? qb : kb;
    unsigned short* dst = mat == 0 ? qh : kh;
    const float scale = mat == 0 ? (0.125f * LOG2E) : 1.0f;
    const int sA = (m0 & 1023) + moff + q15;
    const int nA = n0 + noff + (quad << 2);
#pragma unroll
    for (int i = 0; i < 4; ++i) {
      int colb = nA + i * 16;
      int hh = colb >> 6, dd = colb & 63;
      float bs0 = barr[colb + 0] * scale;
      float bs1 = barr[colb + 1] * scale;
      float bs2 = barr[colb + 2] * scale;
      float bs3 = barr[colb + 3] * scale;
#pragma unroll
      for (int j = 0; j < 4; ++j) {
        int s = sA + j * 16;
        ushort4 pk;
        pk.x = f2bf(__builtin_fmaf(acc[i][j][0], scale, bs0));
        pk.y = f2bf(__builtin_fmaf(acc[i][j][1], scale, bs1));
        pk.z = f2bf(__builtin_fmaf(acc[i][j][2], scale, bs2));
        pk.w = f2bf(__builtin_fmaf(acc[i][j][3], scale, bs3));
        *(ushort4*)&dst[((size_t)(bidx * 16 + hh) * 1024 + s) * 64 + dd] = pk;
      }
    }

    // ---- fused gate (mat==0 only): wave owns head hh0, rows sA + j*16 ----
    if (mat == 0) {
      const int hh0 = (n0 + noff) >> 6;
      float sa_p0 = 0.f, sa_p1 = 0.f, sa_p2 = 0.f, sa_p3 = 0.f;
      float sb_p0 = 0.f, sb_p1 = 0.f, sb_p2 = 0.f, sb_p3 = 0.f;
#pragma unroll
      for (int e = 0; e < 8; ++e) {
        float p0 = 0.f, p1 = 0.f, p2 = 0.f, p3 = 0.f;
#pragma unroll
        for (int i = 0; i < 4; ++i) {
          const int dbase = (quad << 2) + i * 16;  // lane's d for r=0
          float4 w4 = *(const float4*)(grep_w + e * 64 + dbase);
          int colb = nA + i * 16;
          float b0 = qb[colb + 0], b1 = qb[colb + 1];
          float b2 = qb[colb + 2], b3 = qb[colb + 3];
          p0 += (acc[i][0][0] + b0) * w4.x + (acc[i][0][1] + b1) * w4.y +
                (acc[i][0][2] + b2) * w4.z + (acc[i][0][3] + b3) * w4.w;
          p1 += (acc[i][1][0] + b0) * w4.x + (acc[i][1][1] + b1) * w4.y +
                (acc[i][1][2] + b2) * w4.z + (acc[i][1][3] + b3) * w4.w;
          p2 += (acc[i][2][0] + b0) * w4.x + (acc[i][2][1] + b1) * w4.y +
                (acc[i][2][2] + b2) * w4.z + (acc[i][2][3] + b3) * w4.w;
          p3 += (acc[i][3][0] + b0) * w4.x + (acc[i][3][1] + b1) * w4.y +
                (acc[i][3][2] + b2) * w4.z + (acc[i][3][3] + b3) * w4.w;
        }
        if (e < 4) {
          sa_p0 += p0; sa_p1 += p1; sa_p2 += p2; sa_p3 += p3;
        } else {
          sb_p0 += p0; sb_p1 += p1; sb_p2 += p2; sb_p3 += p3;
        }
      }
      // reduce over quad (d-partition partners: lanes differing in bits 4,5)
      sa_p0 += __shfl_xor(sa_p0, 16, 64); sa_p0 += __shfl_xor(sa_p0, 32, 64);
      sa_p1 += __shfl_xor(sa_p1, 16, 64); sa_p1 += __shfl_xor(sa_p1, 32, 64);
      sa_p2 += __shfl_xor(sa_p2, 16, 64); sa_p2 += __shfl_xor(sa_p2, 32, 64);
      sa_p3 += __shfl_xor(sa_p3, 16, 64); sa_p3 += __shfl_xor(sa_p3, 32, 64);
      sb_p0 += __shfl_xor(sb_p0, 16, 64); sb_p0 += __shfl_xor(sb_p0, 32, 64);
      sb_p1 += __shfl_xor(sb_p1, 16, 64); sb_p1 += __shfl_xor(sb_p1, 32, 64);
      sb_p2 += __shfl_xor(sb_p2, 16, 64); sb_p2 += __shfl_xor(sb_p2, 32, 64);
      sb_p3 += __shfl_xor(sb_p3, 16, 64); sb_p3 += __shfl_xor(sb_p3, 32, 64);
      if (quad == 0) {
        const float gb03 = (grep_b[0] + grep_b[1]) + (grep_b[2] + grep_b[3]);
        const float gb47 = (grep_b[4] + grep_b[5]) + (grep_b[6] + grep_b[7]);
        const float ga = grep_a[hh0];
        float* grow = gate + ((size_t)(bidx * 16 + hh0)) * 1024 + sA;
        float sav[4] = {sa_p0, sa_p1, sa_p2, sa_p3};
        float sbv[4] = {sb_p0, sb_p1, sb_p2, sb_p3};
#pragma unroll
        for (int j = 0; j < 4; ++j) {
          float sa = sav[j] * 0.125f + gb03;
          float sb = sbv[j] * 0.125f + gb47;
          float siga = 1.f / (1.f + __expf(-sa));
          float sigb = 1.f / (1.f + __expf(-sb));
          grow[j * 16] = siga * (sigb * ga - 1.f) + 2.f;
        }
      }
    }
  } else {
    const int s00 = (m0 & 1023) + moff + (quad << 2);
    const int c0 = n0 + noff + q15;
#pragma unroll
    for (int j = 0; j < 4; ++j) {
      int col = c0 + j * 16;
      int hh = col >> 6, dd = col & 63;
      float bias = vb[col];
#pragma unroll
      for (int i = 0; i < 4; ++i) {
        int s = s00 + i * 16;
        ushort4 pk;
        pk.x = f2bf(acc[i][j][0] + bias);
        pk.y = f2bf(acc[i][j][1] + bias);
        pk.z = f2bf(acc[i][j][2] + bias);
        pk.w = f2bf(acc[i][j][3] + bias);
        *(ushort4*)&vT[((size_t)(bidx * 16 + hh) * 64 + dd) * 1024 + s] = pk;
      }
    }
  }
}

// ---------------- flash attention v6 (session-best configuration) ----
__global__ __launch_bounds__(512, 4) void attn_kernel(
    const unsigned short* __restrict__ qh, const unsigned short* __restrict__ kh,
    const unsigned short* __restrict__ vT, const float* __restrict__ gate,
    const float* __restrict__ bias_f, unsigned short* __restrict__ ctx) {
  // LDS: K dbuf [0,16K) V dbuf [16K,32K) bias f32 window [33280,+4608)
  // epilogue reuses [0,33280) as Ot fp32[128][65] (col 64 = l partial)
  __shared__ __align__(16) char smem[37888];
  const int tid = threadIdx.x, lane = tid & 63, w = tid >> 6;
  const int qt = w >> 1, khalf = w & 1;
  const int bh = blockIdx.x;  // b*16+h
  const int h = bh & 15;
  const int qs0 = blockIdx.y * 128;
  const int q31 = lane & 31, hb = lane >> 5, q7 = q31 & 7;
  const int sq = qs0 + qt * 32 + q31;

  // bias window: bcf[i] = bias[h][896-qs0+i] (f32), i in [0,1152)
  float* bcf = (float*)(smem + 33280);
  {
    const float* gb = bias_f + h * 2056 + (896 - qs0);
    for (int i = tid; i < 1152; i += 512) bcf[i] = gb[i];
  }

  const char* kbase = (const char*)(kh + (size_t)bh * 65536);
  const char* vbase = (const char*)(vT + (size_t)bh * 65536);

  // staging: 512 threads x 16B = one full 8KB tile per instruction
  const int o = tid * 16;
  const int srow = o >> 7;
  const int sg = ((o >> 4) & 7) ^ (srow & 7);
  const size_t koff = (size_t)srow * 128 + sg * 16;
  const size_t voff = (size_t)srow * 2048 + sg * 16;

  gload_lds16(kbase + koff, smem + o);
  gload_lds16(vbase + voff, smem + 16384 + o);

  // Q B-frags: B[k=d][n=q]: n=q31, k = hb*8 + j within each 16-d chunk
  const unsigned short* qrow = qh + ((size_t)bh * 1024 + sq) * 64 + hb * 8;
  bf16x8 qf[4];
#pragma unroll
  for (int dc = 0; dc < 4; ++dc) qf[dc] = *(const bf16x8*)(qrow + dc * 16);

  const float gate_lane = gate[bh * 1024 + sq];

  // per-lane f32 bias window base: key (kc*64 + khalf*32 + 8rg + 4hb + j)
  // maps to bcf[(qs0+127-sq) + key]
  const int i0 = (qs0 + 127 - sq) + khalf * 32 + hb * 4;

  float l_run = 0.f;
  f32x16 accO0 = {}, accO1 = {};

  for (int kc = 0; kc < 16; ++kc) {
    __syncthreads();  // current buffer's DMA landed; previous buffer free
    const char* Kc = smem + (kc & 1) * 8192;
    const char* Vc = smem + 16384 + (kc & 1) * 8192;
    if (kc < 15) {
      int nb = (kc + 1) & 1;
      gload_lds16(kbase + (size_t)(kc + 1) * 8192 + koff, smem + nb * 8192 + o);
      gload_lds16(vbase + (size_t)(kc + 1) * 128 + voff, smem + 16384 + nb * 8192 + o);
    }

    // ---- sac := gate*bias (C-layout rows: key-in-half = (r&3)+8*(r>>2)+4hb) ----
    f32x16 sac;
    {
      const int ib = i0 + kc * 64;
#pragma unroll
      for (int rg = 0; rg < 4; ++rg) {
        sac[rg * 4 + 0] = gate_lane * bcf[ib + rg * 8 + 0];
        sac[rg * 4 + 1] = gate_lane * bcf[ib + rg * 8 + 1];
        sac[rg * 4 + 2] = gate_lane * bcf[ib + rg * 8 + 2];
        sac[rg * 4 + 3] = gate_lane * bcf[ib + rg * 8 + 3];
      }
    }

    // ---- S^T = K Q^T + gate*bias : wave's 32-key half x 32 q, d=64 in 4 chunks ----
    const char* Krow = Kc + (khalf * 32 + q31) * 128;  // (khalf*32+q31)&7 == q7
    __builtin_amdgcn_s_setprio(1);
#pragma unroll
    for (int ks = 0; ks < 4; ++ks) {
      bf16x8 kf = *(const bf16x8*)(Krow + (((ks * 2 + hb) ^ q7) << 4));
      sac = MFMA32_BF16(kf, qf[ks], sac);
    }
    __builtin_amdgcn_s_setprio(0);

    // ---- exp2 + pack P pairs (lane keys: 8rg+4hb+r within half) ----
    float ps = 0.f;
    unsigned pu[8];
#pragma unroll
    for (int rg = 0; rg < 4; ++rg) {
      float p0 = __builtin_exp2f(sac[rg * 4 + 0]);
      float p1 = __builtin_exp2f(sac[rg * 4 + 1]);
      float p2 = __builtin_exp2f(sac[rg * 4 + 2]);
      float p3 = __builtin_exp2f(sac[rg * 4 + 3]);
      ps += (p0 + p1) + (p2 + p3);
      pu[2 * rg] = pk_bf2(p0, p1);
      pu[2 * rg + 1] = pk_bf2(p2, p3);
    }
    l_run += ps;

    // ---- C->B transform: 4x v_permlane32_swap_b32 ----
    uint32x2 s02 = __builtin_amdgcn_permlane32_swap(pu[0], pu[2], false, false);
    uint32x2 s13 = __builtin_amdgcn_permlane32_swap(pu[1], pu[3], false, false);
    uint32x2 s46 = __builtin_amdgcn_permlane32_swap(pu[4], pu[6], false, false);
    uint32x2 s57 = __builtin_amdgcn_permlane32_swap(pu[5], pu[7], false, false);
    union PB { unsigned u[4]; bf16x8 v; } b0, b1;
    b0.u[0] = s02.x; b0.u[1] = s13.x; b0.u[2] = s02.y; b0.u[3] = s13.y;
    b1.u[0] = s46.x; b1.u[1] = s57.x; b1.u[2] = s46.y; b1.u[3] = s57.y;

    // ---- O^T += V^T P^T over the wave's 32 keys (2 k-chunks of 16) ----
    __builtin_amdgcn_s_setprio(1);
#pragma unroll
    for (int mf = 0; mf < 2; ++mf) {
      bf16x8 pb = mf ? b1.v : b0.v;
      int vch = ((khalf * 4 + mf * 2 + hb) ^ q7) << 4;
      bf16x8 v0f = *(const bf16x8*)(Vc + q31 * 128 + vch);
      bf16x8 v1f = *(const bf16x8*)(Vc + (32 + q31) * 128 + vch);
      accO0 = MFMA32_BF16(v0f, pb, accO0);
      accO1 = MFMA32_BF16(v1f, pb, accO1);
    }
    __builtin_amdgcn_s_setprio(0);
  }

  // combine hb halves (keys interleave mod 8 within the wave's half)
  l_run += __shfl_xor(l_run, 32, 64);

  // ---- epilogue: cross-wave combine + transpose + dense f16 stores ----
  __syncthreads();  // all frag reads done; smem[0,33280) reusable as Ot
  float* Ot = (float*)smem;  // [128][65], col 64 holds kh0's l
  float* ow = Ot + (qt * 32 + q31) * 65;
  if (khalf == 0) {
#pragma unroll
    for (int rr = 0; rr < 16; ++rr) {
      int d = (rr & 3) + 8 * (rr >> 2) + 4 * hb;
      ow[d] = accO0[rr];
      ow[32 + d] = accO1[rr];
    }
    if (hb == 0) ow[64] = l_run;
  }
  __syncthreads();
  if (khalf == 1) {
    float inv = 1.0f / (ow[64] + l_run);
#pragma unroll
    for (int rr = 0; rr < 16; ++rr) {
      int d = (rr & 3) + 8 * (rr >> 2) + 4 * hb;
      ow[d] = (ow[d] + accO0[rr]) * inv;
      ow[32 + d] = (ow[32 + d] + accO1[rr]) * inv;
    }
  }
  __syncthreads();
  {
    int row = tid >> 2, dg = tid & 3;  // 128 rows x 4 d-groups of 16
    int s = qs0 + row;
    const float* src = Ot + row * 65 + dg * 16;
    unsigned short hbuf[16];
#pragma unroll
    for (int j = 0; j < 16; ++j) hbuf[j] = f2h(src[j]);
    size_t base = (size_t)(s * 4 + (bh >> 4)) * 1024 + h * 64 + dg * 16;
    *(uint4*)(ctx + base) = *(const uint4*)(hbuf);
    *(uint4*)(ctx + base + 8) = *(const uint4*)(hbuf + 8);
  }
}

// ---------------- output projection: single f16 GEMM, 64x128 tiles, dbuf DMA ----------------
__global__ __launch_bounds__(256, 3) void outproj_kernel(
    const unsigned short* __restrict__ Af,  // ctx f16 (4096,1024)
    const unsigned short* __restrict__ Bf,  // out_w f16 (1024,1024)
    const float* __restrict__ ob, float* __restrict__ out) {
  // per-buffer: A 4K + B 8K = 12K; x2 = 24K
  __shared__ __align__(16) char smem[24576];
  const int tid = threadIdx.x, lane = tid & 63, wv_ = tid >> 6;
  const int q15 = lane & 15, quad = lane >> 4;
  const int n0 = blockIdx.x * 128;
  const int m0 = blockIdx.y * 64;
  const int moff = (wv_ & 1) * 32;
  const int noff = (wv_ >> 1) * 64;

  const int oa = tid * 16;
  const int ra_ = oa >> 6;
  const int ga_ = (((oa >> 4) & 3) ^ swz(ra_)) << 4;
  int rb_[2], gb_[2], obo_[2];
#pragma unroll
  for (int c = 0; c < 2; ++c) {
    int ob2 = c * 4096 + tid * 16;
    obo_[c] = ob2;
    rb_[c] = ob2 >> 6;
    gb_[c] = (((ob2 >> 4) & 3) ^ swz(rb_[c])) << 4;
  }

#define OP_STAGE(kt, buf)                                                        \
  {                                                                              \
    char* bb = smem + (buf)*12288;                                               \
    size_t ga = (size_t)(m0 + ra_) * 2048 + (size_t)(kt)*64 + ga_;               \
    gload_lds16((const char*)Af + ga, bb + oa);                                  \
    _Pragma("unroll") for (int c = 0; c < 2; ++c) {                              \
      size_t gb = (size_t)(n0 + rb_[c]) * 2048 + (size_t)(kt)*64 + gb_[c];       \
      gload_lds16((const char*)Bf + gb, bb + 4096 + obo_[c]);                    \
    }                                                                            \
  }

  f32x4 acc[4][2] = {};
  OP_STAGE(0, 0);
  for (int kt = 0; kt < 32; ++kt) {
    __syncthreads();
    const char* base = smem + (kt & 1) * 12288;
    if (kt < 31) OP_STAGE(kt + 1, (kt + 1) & 1);

    f16x8 wf[4], cf[2];
#pragma unroll
    for (int i = 0; i < 4; ++i) {
      int rb = noff + i * 16 + q15;
      wf[i] = *(const f16x8*)(base + 4096 + rb * 64 + ((quad ^ swz(rb)) << 4));
    }
#pragma unroll
    for (int j = 0; j < 2; ++j) {
      int ra = moff + j * 16 + q15;
      cf[j] = *(const f16x8*)(base + ra * 64 + ((quad ^ swz(ra)) << 4));
    }
#pragma unroll
    for (int i = 0; i < 4; ++i)
#pragma unroll
      for (int j = 0; j < 2; ++j) acc[i][j] = MFMA_F16(wf[i], cf[j], acc[i][j]);
  }
#undef OP_STAGE

  // acc[i][j]: i -> n-blocks (out cols), j -> s-blocks
  const int sA = m0 + moff + q15;
  const int nA = n0 + noff + (quad << 2);
#pragma unroll
  for (int i = 0; i < 4; ++i) {
    int colb = nA + i * 16;
    float4 b4 = *(const float4*)&ob[colb];
#pragma unroll
    for (int j = 0; j < 2; ++j) {
      int s = sA + j * 16;
      float4 o4;
      o4.x = acc[i][j][0] + b4.x;
      o4.y = acc[i][j][1] + b4.y;
      o4.z = acc[i][j][2] + b4.z;
      o4.w = acc[i][j][3] + b4.w;
      *(float4*)&out[(size_t)s * 1024 + colb] = o4;
    }
  }
}

// ---------------- launcher ----------------
extern "C" void kernel_launch(void* const* d_in, const int* in_sizes, int n_in,
                              void* d_out, int out_size, void* d_ws, size_t ws_size,
                              hipStream_t stream) {
  const float* query = (const float*)d_in[0];
  const float* q_w = (const float*)d_in[1];
  const float* q_b = (const float*)d_in[2];
  const float* k_w = (const float*)d_in[3];
  const float* k_b = (const float*)d_in[4];
  const float* v_w = (const float*)d_in[5];
  const float* v_b = (const float*)d_in[6];
  const float* out_w = (const float*)d_in[7];
  const float* out_b = (const float*)d_in[8];
  const float* rel_emb = (const float*)d_in[9];
  const float* grep_w = (const float*)d_in[10];
  const float* grep_b = (const float*)d_in[11];
  const float* grep_a = (const float*)d_in[12];
  float* out = (float*)d_out;

  const size_t MB = 1u << 20;
  char* ws = (char*)d_ws;
  unsigned short* q_bf = (unsigned short*)(ws);            // (B,S,E) bf16, 8 MB
  unsigned short* wq_bf = (unsigned short*)(ws + 8 * MB);
  unsigned short* wk_bf = (unsigned short*)(ws + 10 * MB);
  unsigned short* wv_bf = (unsigned short*)(ws + 12 * MB);
  unsigned short* ow_h = (unsigned short*)(ws + 14 * MB);  // f16
  unsigned short* qhp = (unsigned short*)(ws + 16 * MB);   // (B,H,S,D)
  unsigned short* khp = (unsigned short*)(ws + 24 * MB);   // (B,H,S,D)
  unsigned short* vTp = (unsigned short*)(ws + 32 * MB);   // (B,H,D,S)
  unsigned short* ctxp = (unsigned short*)(ws + 40 * MB);  // (S*B,E) f16
  float* gatep = (float*)(ws + 48 * MB);
  float* biasp = (float*)(ws + 48 * MB + 256 * 1024);      // f32 16x2056

  prep_kernel<<<5129, 256, 0, stream>>>(query, q_w, k_w, v_w, out_w, rel_emb, q_bf, wq_bf,
                                        wk_bf, wv_bf, ow_h, biasp);
  qkv_gemm_kernel<<<dim3(24, 32), 256, 0, stream>>>(q_bf, wq_bf, wk_bf, wv_bf, q_b, k_b, v_b,
                                                    grep_w, grep_b, grep_a, qhp, khp, vTp,
                                                    gatep);
  attn_kernel<<<dim3(64, 8), 512, 0, stream>>>(qhp, khp, vTp, gatep, biasp, ctxp);
  outproj_kernel<<<dim3(8, 64), 256, 0, stream>>>(ctxp, ow_h, out_b, out);
}

// Round 13
// 188.665 us; speedup vs baseline: 1.0290x; 1.0290x over previous
//
#include <hip/hip_runtime.h>
#include <hip/hip_bf16.h>
#include <stdint.h>

// Problem dims (fixed): S=1024, B=4, E=1024, H=16, D=64, M=S*B=4096
// scaling = D^-0.5 = 0.125; log2e folded into q-scale and bias table so the
// attention softmax uses raw exp2.

typedef short bf16x8 __attribute__((ext_vector_type(8)));
typedef _Float16 f16x8 __attribute__((ext_vector_type(8)));
typedef float f32x4 __attribute__((ext_vector_type(4)));
typedef float f32x16 __attribute__((ext_vector_type(16)));
typedef unsigned uint32x2 __attribute__((ext_vector_type(2)));

#define MFMA_BF16(a, b, c) __builtin_amdgcn_mfma_f32_16x16x32_bf16((a), (b), (c), 0, 0, 0)
#define MFMA_F16(a, b, c) __builtin_amdgcn_mfma_f32_16x16x32_f16((a), (b), (c), 0, 0, 0)
#define MFMA32_BF16(a, b, c) __builtin_amdgcn_mfma_f32_32x32x16_bf16((a), (b), (c), 0, 0, 0)

#define LOG2E 1.44269504088896f
#define LN2 0.693147180559945f

__device__ __forceinline__ unsigned short f2bf(float x) {
  union { float f; unsigned u; } v; v.f = x;
  unsigned r = v.u + 0x7fffu + ((v.u >> 16) & 1u);  // RNE
  return (unsigned short)(r >> 16);
}
__device__ __forceinline__ float bf2f(unsigned short u) {
  union { unsigned u; float f; } v; v.u = ((unsigned)u) << 16;
  return v.f;
}
__device__ __forceinline__ unsigned short f2h(float x) {  // RNE via v_cvt_f16_f32
  union { _Float16 h; unsigned short u; } v; v.h = (_Float16)x;
  return v.u;
}
// pack 2 fp32 -> 2 bf16 (RNE) in one u32 (v_cvt_pk_bf16_f32 on gfx950)
__device__ __forceinline__ unsigned pk_bf2(float a, float b) {
  union { __hip_bfloat162 h2; unsigned u; } v;
  v.h2 = __float22bfloat162_rn(float2{a, b});
  return v.u;
}

// async global->LDS 16B: lane's data lands at (wave-uniform base) + lane*16.
__device__ __forceinline__ void gload_lds16(const void* g, void* l) {
  __builtin_amdgcn_global_load_lds(
      (const __attribute__((address_space(1))) unsigned int*)g,
      (__attribute__((address_space(3))) unsigned int*)l, 16, 0, 0);
}

// LDS chunk swizzle for 64B rows (4 chunks of 16B)
__device__ __forceinline__ int swz(int row) { return (row ^ (row >> 2)) & 3; }

// ---------------- fused prep: query cvt/transpose + weight prep + relbias ----------------
__global__ __launch_bounds__(256) void prep_kernel(
    const float* __restrict__ query, const float* __restrict__ q_w,
    const float* __restrict__ k_w, const float* __restrict__ v_w,
    const float* __restrict__ out_w, const float* __restrict__ rel_emb,
    unsigned short* __restrict__ q_bf, unsigned short* __restrict__ wq,
    unsigned short* __restrict__ wk, unsigned short* __restrict__ wv,
    unsigned short* __restrict__ ow_h,   // f16 out_w
    float* __restrict__ bias_f) {        // f32, 16 x 2056 (last 9 zero-padded)
  int i = blockIdx.x * 256 + threadIdx.x;
  if (i < 1048576) {
    // query: (S,B,E) fp32 -> (B,S,E) bf16, 4 elems per thread
    int e4 = (i & 255) << 2;
    int sb = i >> 8;
    int s = sb >> 2, b = sb & 3;
    float4 q4 = *(const float4*)(query + ((size_t)i << 2));
    ushort4 o;
    o.x = f2bf(q4.x); o.y = f2bf(q4.y); o.z = f2bf(q4.z); o.w = f2bf(q4.w);
    *(ushort4*)&q_bf[((size_t)(b * 1024 + s) << 10) | e4] = o;
  } else if (i < 1310720) {
    int j = (i - 1048576) << 2;
    float4 a = *(const float4*)(q_w + j);
    float4 b = *(const float4*)(k_w + j);
    float4 c = *(const float4*)(v_w + j);
    float4 d = *(const float4*)(out_w + j);
    ushort4 o;
    o.x = f2bf(a.x); o.y = f2bf(a.y); o.z = f2bf(a.z); o.w = f2bf(a.w);
    *(ushort4*)&wq[j] = o;
    o.x = f2bf(b.x); o.y = f2bf(b.y); o.z = f2bf(b.z); o.w = f2bf(b.w);
    *(ushort4*)&wk[j] = o;
    o.x = f2bf(c.x); o.y = f2bf(c.y); o.z = f2bf(c.z); o.w = f2bf(c.w);
    *(ushort4*)&wv[j] = o;
    o.x = f2h(d.x); o.y = f2h(d.y); o.z = f2h(d.z); o.w = f2h(d.w);
    *(ushort4*)&ow_h[j] = o;
  } else {
    int idx = i - 1310720;
    if (idx >= 2056) return;
    if (idx >= 2047) {
#pragma unroll
      for (int h = 0; h < 16; ++h) bias_f[h * 2056 + idx] = 0.f;
      return;
    }
    int rel = idx - 1023;
    int n = rel < 0 ? -rel : rel;
    int ret = rel > 0 ? 16 : 0;
    int bucket;
    if (n < 8) {
      bucket = ret + n;
    } else {
      int large = 8 + (int)(logf((float)n / 8.0f) / logf(16.0f) * 8.0f);
      if (large > 15) large = 15;
      bucket = ret + large;
    }
#pragma unroll
    for (int h = 0; h < 16; ++h)
      bias_f[h * 2056 + idx] = rel_emb[bucket * 16 + h] * LOG2E;
  }
}

// ---------------- fused QKV projection GEMM + gate (BK=32, dbuf DMA) ----------------
// R22: revert R21's BK=64 (refuted per pre-commitment: occupancy 24->14.5%
// at 64KB LDS cost more than the halved barrier count gained; qkv 42.4->46.2,
// reproducing m132's BK-upsize regression). This is the R20 version: BK=32,
// 32KB LDS, 3 blocks/CU, gate fused in the mat==0 epilogue from registers.
__global__ __launch_bounds__(256, 3) void qkv_gemm_kernel(
    const unsigned short* __restrict__ A, const unsigned short* __restrict__ Wq,
    const unsigned short* __restrict__ Wk, const unsigned short* __restrict__ Wv,
    const float* __restrict__ qb, const float* __restrict__ kb, const float* __restrict__ vb,
    const float* __restrict__ grep_w, const float* __restrict__ grep_b,
    const float* __restrict__ grep_a,
    unsigned short* __restrict__ qh,   // (B,H,S,D) scaled q
    unsigned short* __restrict__ kh,   // (B,H,S,D)
    unsigned short* __restrict__ vT,   // (B,H,D,S)
    float* __restrict__ gate)          // (B*H, S)
{
  __shared__ __align__(16) char smem[32768];
  const int tid = threadIdx.x, lane = tid & 63;
  const int wv_ = tid >> 6;
  const int nt = blockIdx.x;
  const int mt = blockIdx.y;
  const int mat = nt >> 3;
  const unsigned short* W = mat == 0 ? Wq : (mat == 1 ? Wk : Wv);
  const int n0 = (nt & 7) * 128;
  const int m0 = mt * 128;
  const int moff = (wv_ & 1) * 64;
  const int noff = (wv_ >> 1) * 64;
  const int q15 = lane & 15, quad = lane >> 4;

  // operand-role select (uniform per block): q/k read af from the W region.
  const int abase = (mat < 2) ? 8192 : 0;
  const int bbase2 = 8192 - abase;
  const int aoff = (mat < 2) ? noff : moff;
  const int boff = (mat < 2) ? moff : noff;

  f32x4 acc[4][4] = {};
  const char* Ab = (const char*)A;
  const char* Wb = (const char*)W;

  int st_row[2], st_g[2];
#pragma unroll
  for (int c = 0; c < 2; ++c) {
    int o = c * 4096 + tid * 16;
    int row = o >> 6, p = (o >> 4) & 3;
    st_row[c] = row;
    st_g[c] = p ^ swz(row);
  }

#define QKV_STAGE(kt, buf)                                                     \
  {                                                                            \
    char* bb = smem + (buf)*16384;                                             \
    _Pragma("unroll") for (int c = 0; c < 2; ++c) {                            \
      int o = c * 4096 + tid * 16;                                             \
      size_t ga = (size_t)(m0 + st_row[c]) * 2048 + (size_t)(kt)*64 + st_g[c] * 16; \
      size_t gb = (size_t)(n0 + st_row[c]) * 2048 + (size_t)(kt)*64 + st_g[c] * 16; \
      gload_lds16(Ab + ga, bb + o);                                            \
      gload_lds16(Wb + gb, bb + 8192 + o);                                     \
    }                                                                          \
  }

  QKV_STAGE(0, 0);
  for (int kt = 0; kt < 32; ++kt) {
    __syncthreads();
    const char* base = smem + (kt & 1) * 16384;
    if (kt < 31) QKV_STAGE(kt + 1, (kt + 1) & 1);

    bf16x8 af[4], bfr[4];
#pragma unroll
    for (int i = 0; i < 4; ++i) {
      int ra = aoff + i * 16 + q15;
      int rb = boff + i * 16 + q15;
      af[i] = *(const bf16x8*)(base + abase + ra * 64 + ((quad ^ swz(ra)) << 4));
      bfr[i] = *(const bf16x8*)(base + bbase2 + rb * 64 + ((quad ^ swz(rb)) << 4));
    }
#pragma unroll
    for (int i = 0; i < 4; ++i)
#pragma unroll
      for (int j = 0; j < 4; ++j) acc[i][j] = MFMA_BF16(af[i], bfr[j], acc[i][j]);
  }
#undef QKV_STAGE

  const int bidx = m0 >> 10;
  if (mat < 2) {
    // acc[i][j]: i -> n-blocks (d-dim rows), j -> s-blocks (cols)
    const float* barr = mat == 0 ? qb : kb;
    unsigned short* dst = mat == 0 ? qh : kh;
    const float scale = mat == 0 ? (0.125f * LOG2E) : 1.0f;
    const int sA = (m0 & 1023) + moff + q15;
    const int nA = n0 + noff + (quad << 2);
#pragma unroll
    for (int i = 0; i < 4; ++i) {
      int colb = nA + i * 16;
      int hh = colb >> 6, dd = colb & 63;
      float bs0 = barr[colb + 0] * scale;
      float bs1 = barr[colb + 1] * scale;
      float bs2 = barr[colb + 2] * scale;
      float bs3 = barr[colb + 3] * scale;
#pragma unroll
      for (int j = 0; j < 4; ++j) {
        int s = sA + j * 16;
        ushort4 pk;
        pk.x = f2bf(__builtin_fmaf(acc[i][j][0], scale, bs0));
        pk.y = f2bf(__builtin_fmaf(acc[i][j][1], scale, bs1));
        pk.z = f2bf(__builtin_fmaf(acc[i][j][2], scale, bs2));
        pk.w = f2bf(__builtin_fmaf(acc[i][j][3], scale, bs3));
        *(ushort4*)&dst[((size_t)(bidx * 16 + hh) * 1024 + s) * 64 + dd] = pk;
      }
    }

    // ---- fused gate (mat==0 only): wave owns head hh0, rows sA + j*16 ----
    if (mat == 0) {
      const int hh0 = (n0 + noff) >> 6;
      float sa_p0 = 0.f, sa_p1 = 0.f, sa_p2 = 0.f, sa_p3 = 0.f;
      float sb_p0 = 0.f, sb_p1 = 0.f, sb_p2 = 0.f, sb_p3 = 0.f;
#pragma unroll
      for (int e = 0; e < 8; ++e) {
        float p0 = 0.f, p1 = 0.f, p2 = 0.f, p3 = 0.f;
#pragma unroll
        for (int i = 0; i < 4; ++i) {
          const int dbase = (quad << 2) + i * 16;  // lane's d for r=0
          float4 w4 = *(const float4*)(grep_w + e * 64 + dbase);
          int colb = nA + i * 16;
          float b0 = qb[colb + 0], b1 = qb[colb + 1];
          float b2 = qb[colb + 2], b3 = qb[colb + 3];
          p0 += (acc[i][0][0] + b0) * w4.x + (acc[i][0][1] + b1) * w4.y +
                (acc[i][0][2] + b2) * w4.z + (acc[i][0][3] + b3) * w4.w;
          p1 += (acc[i][1][0] + b0) * w4.x + (acc[i][1][1] + b1) * w4.y +
                (acc[i][1][2] + b2) * w4.z + (acc[i][1][3] + b3) * w4.w;
          p2 += (acc[i][2][0] + b0) * w4.x + (acc[i][2][1] + b1) * w4.y +
                (acc[i][2][2] + b2) * w4.z + (acc[i][2][3] + b3) * w4.w;
          p3 += (acc[i][3][0] + b0) * w4.x + (acc[i][3][1] + b1) * w4.y +
                (acc[i][3][2] + b2) * w4.z + (acc[i][3][3] + b3) * w4.w;
        }
        if (e < 4) {
          sa_p0 += p0; sa_p1 += p1; sa_p2 += p2; sa_p3 += p3;
        } else {
          sb_p0 += p0; sb_p1 += p1; sb_p2 += p2; sb_p3 += p3;
        }
      }
      // reduce over quad (d-partition partners: lanes differing in bits 4,5)
      sa_p0 += __shfl_xor(sa_p0, 16, 64); sa_p0 += __shfl_xor(sa_p0, 32, 64);
      sa_p1 += __shfl_xor(sa_p1, 16, 64); sa_p1 += __shfl_xor(sa_p1, 32, 64);
      sa_p2 += __shfl_xor(sa_p2, 16, 64); sa_p2 += __shfl_xor(sa_p2, 32, 64);
      sa_p3 += __shfl_xor(sa_p3, 16, 64); sa_p3 += __shfl_xor(sa_p3, 32, 64);
      sb_p0 += __shfl_xor(sb_p0, 16, 64); sb_p0 += __shfl_xor(sb_p0, 32, 64);
      sb_p1 += __shfl_xor(sb_p1, 16, 64); sb_p1 += __shfl_xor(sb_p1, 32, 64);
      sb_p2 += __shfl_xor(sb_p2, 16, 64); sb_p2 += __shfl_xor(sb_p2, 32, 64);
      sb_p3 += __shfl_xor(sb_p3, 16, 64); sb_p3 += __shfl_xor(sb_p3, 32, 64);
      if (quad == 0) {
        const float gb03 = (grep_b[0] + grep_b[1]) + (grep_b[2] + grep_b[3]);
        const float gb47 = (grep_b[4] + grep_b[5]) + (grep_b[6] + grep_b[7]);
        const float ga = grep_a[hh0];
        float* grow = gate + ((size_t)(bidx * 16 + hh0)) * 1024 + sA;
        float sav[4] = {sa_p0, sa_p1, sa_p2, sa_p3};
        float sbv[4] = {sb_p0, sb_p1, sb_p2, sb_p3};
#pragma unroll
        for (int j = 0; j < 4; ++j) {
          float sa = sav[j] * 0.125f + gb03;
          float sb = sbv[j] * 0.125f + gb47;
          float siga = 1.f / (1.f + __expf(-sa));
          float sigb = 1.f / (1.f + __expf(-sb));
          grow[j * 16] = siga * (sigb * ga - 1.f) + 2.f;
        }
      }
    }
  } else {
    const int s00 = (m0 & 1023) + moff + (quad << 2);
    const int c0 = n0 + noff + q15;
#pragma unroll
    for (int j = 0; j < 4; ++j) {
      int col = c0 + j * 16;
      int hh = col >> 6, dd = col & 63;
      float bias = vb[col];
#pragma unroll
      for (int i = 0; i < 4; ++i) {
        int s = s00 + i * 16;
        ushort4 pk;
        pk.x = f2bf(acc[i][j][0] + bias);
        pk.y = f2bf(acc[i][j][1] + bias);
        pk.z = f2bf(acc[i][j][2] + bias);
        pk.w = f2bf(acc[i][j][3] + bias);
        *(ushort4*)&vT[((size_t)(bidx * 16 + hh) * 64 + dd) * 1024 + s] = pk;
      }
    }
  }
}

// ---------------- flash attention v6 (session-best configuration) ----
__global__ __launch_bounds__(512, 4) void attn_kernel(
    const unsigned short* __restrict__ qh, const unsigned short* __restrict__ kh,
    const unsigned short* __restrict__ vT, const float* __restrict__ gate,
    const float* __restrict__ bias_f, unsigned short* __restrict__ ctx) {
  // LDS: K dbuf [0,16K) V dbuf [16K,32K) bias f32 window [33280,+4608)
  // epilogue reuses [0,33280) as Ot fp32[128][65] (col 64 = l partial)
  __shared__ __align__(16) char smem[37888];
  const int tid = threadIdx.x, lane = tid & 63, w = tid >> 6;
  const int qt = w >> 1, khalf = w & 1;
  const int bh = blockIdx.x;  // b*16+h
  const int h = bh & 15;
  const int qs0 = blockIdx.y * 128;
  const int q31 = lane & 31, hb = lane >> 5, q7 = q31 & 7;
  const int sq = qs0 + qt * 32 + q31;

  // bias window: bcf[i] = bias[h][896-qs0+i] (f32), i in [0,1152)
  float* bcf = (float*)(smem + 33280);
  {
    const float* gb = bias_f + h * 2056 + (896 - qs0);
    for (int i = tid; i < 1152; i += 512) bcf[i] = gb[i];
  }

  const char* kbase = (const char*)(kh + (size_t)bh * 65536);
  const char* vbase = (const char*)(vT + (size_t)bh * 65536);

  // staging: 512 threads x 16B = one full 8KB tile per instruction
  const int o = tid * 16;
  const int srow = o >> 7;
  const int sg = ((o >> 4) & 7) ^ (srow & 7);
  const size_t koff = (size_t)srow * 128 + sg * 16;
  const size_t voff = (size_t)srow * 2048 + sg * 16;

  gload_lds16(kbase + koff, smem + o);
  gload_lds16(vbase + voff, smem + 16384 + o);

  // Q B-frags: B[k=d][n=q]: n=q31, k = hb*8 + j within each 16-d chunk
  const unsigned short* qrow = qh + ((size_t)bh * 1024 + sq) * 64 + hb * 8;
  bf16x8 qf[4];
#pragma unroll
  for (int dc = 0; dc < 4; ++dc) qf[dc] = *(const bf16x8*)(qrow + dc * 16);

  const float gate_lane = gate[bh * 1024 + sq];

  // per-lane f32 bias window base: key (kc*64 + khalf*32 + 8rg + 4hb + j)
  // maps to bcf[(qs0+127-sq) + key]
  const int i0 = (qs0 + 127 - sq) + khalf * 32 + hb * 4;

  float l_run = 0.f;
  f32x16 accO0 = {}, accO1 = {};

  for (int kc = 0; kc < 16; ++kc) {
    __syncthreads();  // current buffer's DMA landed; previous buffer free
    const char* Kc = smem + (kc & 1) * 8192;
    const char* Vc = smem + 16384 + (kc & 1) * 8192;
    if (kc < 15) {
      int nb = (kc + 1) & 1;
      gload_lds16(kbase + (size_t)(kc + 1) * 8192 + koff, smem + nb * 8192 + o);
      gload_lds16(vbase + (size_t)(kc + 1) * 128 + voff, smem + 16384 + nb * 8192 + o);
    }

    // ---- sac := gate*bias (C-layout rows: key-in-half = (r&3)+8*(r>>2)+4hb) ----
    f32x16 sac;
    {
      const int ib = i0 + kc * 64;
#pragma unroll
      for (int rg = 0; rg < 4; ++rg) {
        sac[rg * 4 + 0] = gate_lane * bcf[ib + rg * 8 + 0];
        sac[rg * 4 + 1] = gate_lane * bcf[ib + rg * 8 + 1];
        sac[rg * 4 + 2] = gate_lane * bcf[ib + rg * 8 + 2];
        sac[rg * 4 + 3] = gate_lane * bcf[ib + rg * 8 + 3];
      }
    }

    // ---- S^T = K Q^T + gate*bias : wave's 32-key half x 32 q, d=64 in 4 chunks ----
    const char* Krow = Kc + (khalf * 32 + q31) * 128;  // (khalf*32+q31)&7 == q7
    __builtin_amdgcn_s_setprio(1);
#pragma unroll
    for (int ks = 0; ks < 4; ++ks) {
      bf16x8 kf = *(const bf16x8*)(Krow + (((ks * 2 + hb) ^ q7) << 4));
      sac = MFMA32_BF16(kf, qf[ks], sac);
    }
    __builtin_amdgcn_s_setprio(0);

    // ---- exp2 + pack P pairs (lane keys: 8rg+4hb+r within half) ----
    float ps = 0.f;
    unsigned pu[8];
#pragma unroll
    for (int rg = 0; rg < 4; ++rg) {
      float p0 = __builtin_exp2f(sac[rg * 4 + 0]);
      float p1 = __builtin_exp2f(sac[rg * 4 + 1]);
      float p2 = __builtin_exp2f(sac[rg * 4 + 2]);
      float p3 = __builtin_exp2f(sac[rg * 4 + 3]);
      ps += (p0 + p1) + (p2 + p3);
      pu[2 * rg] = pk_bf2(p0, p1);
      pu[2 * rg + 1] = pk_bf2(p2, p3);
    }
    l_run += ps;

    // ---- C->B transform: 4x v_permlane32_swap_b32 ----
    uint32x2 s02 = __builtin_amdgcn_permlane32_swap(pu[0], pu[2], false, false);
    uint32x2 s13 = __builtin_amdgcn_permlane32_swap(pu[1], pu[3], false, false);
    uint32x2 s46 = __builtin_amdgcn_permlane32_swap(pu[4], pu[6], false, false);
    uint32x2 s57 = __builtin_amdgcn_permlane32_swap(pu[5], pu[7], false, false);
    union PB { unsigned u[4]; bf16x8 v; } b0, b1;
    b0.u[0] = s02.x; b0.u[1] = s13.x; b0.u[2] = s02.y; b0.u[3] = s13.y;
    b1.u[0] = s46.x; b1.u[1] = s57.x; b1.u[2] = s46.y; b1.u[3] = s57.y;

    // ---- O^T += V^T P^T over the wave's 32 keys (2 k-chunks of 16) ----
    __builtin_amdgcn_s_setprio(1);
#pragma unroll
    for (int mf = 0; mf < 2; ++mf) {
      bf16x8 pb = mf ? b1.v : b0.v;
      int vch = ((khalf * 4 + mf * 2 + hb) ^ q7) << 4;
      bf16x8 v0f = *(const bf16x8*)(Vc + q31 * 128 + vch);
      bf16x8 v1f = *(const bf16x8*)(Vc + (32 + q31) * 128 + vch);
      accO0 = MFMA32_BF16(v0f, pb, accO0);
      accO1 = MFMA32_BF16(v1f, pb, accO1);
    }
    __builtin_amdgcn_s_setprio(0);
  }

  // combine hb halves (keys interleave mod 8 within the wave's half)
  l_run += __shfl_xor(l_run, 32, 64);

  // ---- epilogue: cross-wave combine + transpose + dense f16 stores ----
  __syncthreads();  // all frag reads done; smem[0,33280) reusable as Ot
  float* Ot = (float*)smem;  // [128][65], col 64 holds kh0's l
  float* ow = Ot + (qt * 32 + q31) * 65;
  if (khalf == 0) {
#pragma unroll
    for (int rr = 0; rr < 16; ++rr) {
      int d = (rr & 3) + 8 * (rr >> 2) + 4 * hb;
      ow[d] = accO0[rr];
      ow[32 + d] = accO1[rr];
    }
    if (hb == 0) ow[64] = l_run;
  }
  __syncthreads();
  if (khalf == 1) {
    float inv = 1.0f / (ow[64] + l_run);
#pragma unroll
    for (int rr = 0; rr < 16; ++rr) {
      int d = (rr & 3) + 8 * (rr >> 2) + 4 * hb;
      ow[d] = (ow[d] + accO0[rr]) * inv;
      ow[32 + d] = (ow[32 + d] + accO1[rr]) * inv;
    }
  }
  __syncthreads();
  {
    int row = tid >> 2, dg = tid & 3;  // 128 rows x 4 d-groups of 16
    int s = qs0 + row;
    const float* src = Ot + row * 65 + dg * 16;
    unsigned short hbuf[16];
#pragma unroll
    for (int j = 0; j < 16; ++j) hbuf[j] = f2h(src[j]);
    size_t base = (size_t)(s * 4 + (bh >> 4)) * 1024 + h * 64 + dg * 16;
    *(uint4*)(ctx + base) = *(const uint4*)(hbuf);
    *(uint4*)(ctx + base + 8) = *(const uint4*)(hbuf + 8);
  }
}

// ---------------- output projection: single f16 GEMM, 64x128 tiles, dbuf DMA ----------------
__global__ __launch_bounds__(256, 3) void outproj_kernel(
    const unsigned short* __restrict__ Af,  // ctx f16 (4096,1024)
    const unsigned short* __restrict__ Bf,  // out_w f16 (1024,1024)
    const float* __restrict__ ob, float* __restrict__ out) {
  // per-buffer: A 4K + B 8K = 12K; x2 = 24K
  __shared__ __align__(16) char smem[24576];
  const int tid = threadIdx.x, lane = tid & 63, wv_ = tid >> 6;
  const int q15 = lane & 15, quad = lane >> 4;
  const int n0 = blockIdx.x * 128;
  const int m0 = blockIdx.y * 64;
  const int moff = (wv_ & 1) * 32;
  const int noff = (wv_ >> 1) * 64;

  const int oa = tid * 16;
  const int ra_ = oa >> 6;
  const int ga_ = (((oa >> 4) & 3) ^ swz(ra_)) << 4;
  int rb_[2], gb_[2], obo_[2];
#pragma unroll
  for (int c = 0; c < 2; ++c) {
    int ob2 = c * 4096 + tid * 16;
    obo_[c] = ob2;
    rb_[c] = ob2 >> 6;
    gb_[c] = (((ob2 >> 4) & 3) ^ swz(rb_[c])) << 4;
  }

#define OP_STAGE(kt, buf)                                                        \
  {                                                                              \
    char* bb = smem + (buf)*12288;                                               \
    size_t ga = (size_t)(m0 + ra_) * 2048 + (size_t)(kt)*64 + ga_;               \
    gload_lds16((const char*)Af + ga, bb + oa);                                  \
    _Pragma("unroll") for (int c = 0; c < 2; ++c) {                              \
      size_t gb = (size_t)(n0 + rb_[c]) * 2048 + (size_t)(kt)*64 + gb_[c];       \
      gload_lds16((const char*)Bf + gb, bb + 4096 + obo_[c]);                    \
    }                                                                            \
  }

  f32x4 acc[4][2] = {};
  OP_STAGE(0, 0);
  for (int kt = 0; kt < 32; ++kt) {
    __syncthreads();
    const char* base = smem + (kt & 1) * 12288;
    if (kt < 31) OP_STAGE(kt + 1, (kt + 1) & 1);

    f16x8 wf[4], cf[2];
#pragma unroll
    for (int i = 0; i < 4; ++i) {
      int rb = noff + i * 16 + q15;
      wf[i] = *(const f16x8*)(base + 4096 + rb * 64 + ((quad ^ swz(rb)) << 4));
    }
#pragma unroll
    for (int j = 0; j < 2; ++j) {
      int ra = moff + j * 16 + q15;
      cf[j] = *(const f16x8*)(base + ra * 64 + ((quad ^ swz(ra)) << 4));
    }
#pragma unroll
    for (int i = 0; i < 4; ++i)
#pragma unroll
      for (int j = 0; j < 2; ++j) acc[i][j] = MFMA_F16(wf[i], cf[j], acc[i][j]);
  }
#undef OP_STAGE

  // acc[i][j]: i -> n-blocks (out cols), j -> s-blocks
  const int sA = m0 + moff + q15;
  const int nA = n0 + noff + (quad << 2);
#pragma unroll
  for (int i = 0; i < 4; ++i) {
    int colb = nA + i * 16;
    float4 b4 = *(const float4*)&ob[colb];
#pragma unroll
    for (int j = 0; j < 2; ++j) {
      int s = sA + j * 16;
      float4 o4;
      o4.x = acc[i][j][0] + b4.x;
      o4.y = acc[i][j][1] + b4.y;
      o4.z = acc[i][j][2] + b4.z;
      o4.w = acc[i][j][3] + b4.w;
      *(float4*)&out[(size_t)s * 1024 + colb] = o4;
    }
  }
}

// ---------------- launcher ----------------
extern "C" void kernel_launch(void* const* d_in, const int* in_sizes, int n_in,
                              void* d_out, int out_size, void* d_ws, size_t ws_size,
                              hipStream_t stream) {
  const float* query = (const float*)d_in[0];
  const float* q_w = (const float*)d_in[1];
  const float* q_b = (const float*)d_in[2];
  const float* k_w = (const float*)d_in[3];
  const float* k_b = (const float*)d_in[4];
  const float* v_w = (const float*)d_in[5];
  const float* v_b = (const float*)d_in[6];
  const float* out_w = (const float*)d_in[7];
  const float* out_b = (const float*)d_in[8];
  const float* rel_emb = (const float*)d_in[9];
  const float* grep_w = (const float*)d_in[10];
  const float* grep_b = (const float*)d_in[11];
  const float* grep_a = (const float*)d_in[12];
  float* out = (float*)d_out;

  const size_t MB = 1u << 20;
  char* ws = (char*)d_ws;
  unsigned short* q_bf = (unsigned short*)(ws);            // (B,S,E) bf16, 8 MB
  unsigned short* wq_bf = (unsigned short*)(ws + 8 * MB);
  unsigned short* wk_bf = (unsigned short*)(ws + 10 * MB);
  unsigned short* wv_bf = (unsigned short*)(ws + 12 * MB);
  unsigned short* ow_h = (unsigned short*)(ws + 14 * MB);  // f16
  unsigned short* qhp = (unsigned short*)(ws + 16 * MB);   // (B,H,S,D)
  unsigned short* khp = (unsigned short*)(ws + 24 * MB);   // (B,H,S,D)
  unsigned short* vTp = (unsigned short*)(ws + 32 * MB);   // (B,H,D,S)
  unsigned short* ctxp = (unsigned short*)(ws + 40 * MB);  // (S*B,E) f16
  float* gatep = (float*)(ws + 48 * MB);
  float* biasp = (float*)(ws + 48 * MB + 256 * 1024);      // f32 16x2056

  prep_kernel<<<5129, 256, 0, stream>>>(query, q_w, k_w, v_w, out_w, rel_emb, q_bf, wq_bf,
                                        wk_bf, wv_bf, ow_h, biasp);
  qkv_gemm_kernel<<<dim3(24, 32), 256, 0, stream>>>(q_bf, wq_bf, wk_bf, wv_bf, q_b, k_b, v_b,
                                                    grep_w, grep_b, grep_a, qhp, khp, vTp,
                                                    gatep);
  attn_kernel<<<dim3(64, 8), 512, 0, stream>>>(qhp, khp, vTp, gatep, biasp, ctxp);
  outproj_kernel<<<dim3(8, 64), 256, 0, stream>>>(ctxp, ow_h, out_b, out);
}